// Round 16
// baseline (354.396 us; speedup 1.0000x reference)
//
#include <hip/hip_runtime.h>
#include <hip/hip_bf16.h>
#include <cstdint>
#include <cstddef>

// Problem constants (match reference)
constexpr int NB = 2048;            // batch
constexpr int NM = 64;              // neighbors M
constexpr int ND = 64;              // dim
constexpr int NBM = NB * NM;        // 131072 (one layer of an index tensor)
constexpr int NROWS = 3 * NB;       // 6144 rows per stack (L+1 = 3)
constexpr int STACK = 3 * NB * ND;  // 393216 floats per stack
constexpr int NZ = 8;               // lse column splits
constexpr int NE = 100000;          // entity rows
constexpr int NR = 200;             // relation rows
constexpr int NCONV4 = (NE + NR) * ND / 4;   // 1,603,200 float4 conversions
constexpr int NCONVBLK = (NCONV4 + 255) / 256;  // 6263
constexpr int NW1BLK = 16384 / 256;  // 64

typedef __attribute__((ext_vector_type(8))) short short8;
typedef __attribute__((ext_vector_type(4))) float float4v;

__device__ __forceinline__ float wsum(float v) {
#pragma unroll
  for (int o = 32; o > 0; o >>= 1) v += __shfl_xor(v, o, 64);
  return v;
}

__device__ __forceinline__ float wmax(float v) {
#pragma unroll
  for (int o = 32; o > 0; o >>= 1) v = fmaxf(v, __shfl_xor(v, o, 64));
  return v;
}

__device__ __forceinline__ float rcpf(float x) { return __builtin_amdgcn_rcpf(x); }
__device__ __forceinline__ float sqf(float x) { return __builtin_amdgcn_sqrtf(x); }

__device__ __forceinline__ float fast_tanh(float x) {
  float t = __expf(2.f * x);
  return (t - 1.f) * rcpf(t + 1.f);
}

// artanh(clip(x, -1+1e-5, 1-1e-5))
__device__ __forceinline__ float artanh_clip(float x) {
  x = fminf(fmaxf(x, -1.f + 1e-5f), 1.f - 1e-5f);
  return 0.5f * __logf((1.f + x) * rcpf(1.f - x));
}

// fp32 -> bf16 round-half-up (error <= 0.5 ulp; 2 VALU ops)
__device__ __forceinline__ ushort f2bf(float f) {
  return (ushort)((__float_as_uint(f) + 0x8000u) >> 16);
}
__device__ __forceinline__ float bf2f(ushort u) {
  return __uint_as_float((uint)u << 16);
}
// pack two floats as bf16 pair (a in low, b in high)
__device__ __forceinline__ uint pack_bf2(float a, float b) {
  uint au = __float_as_uint(a) + 0x8000u;
  uint bu = __float_as_uint(b) + 0x8000u;
  return __builtin_amdgcn_perm(bu, au, 0x07060302);
}
__device__ __forceinline__ float hp_lo(uint v) { return __uint_as_float(v << 16); }
__device__ __forceinline__ float hp_hi(uint v) { return __uint_as_float(v & 0xFFFF0000u); }

// broadcast a float from lane l (wave-uniform l)
__device__ __forceinline__ float readlane_f(float v, int l) {
  return __int_as_float(__builtin_amdgcn_readlane(__float_as_int(v), l));
}

// normalized bf16 write of a full row held lane=dim (call from one wave)
__device__ __forceinline__ void write_row_norm(
    float v, float* __restrict__ frow, ushort* __restrict__ nrow, int lane) {
  float nv = wsum(v * v);
  float r = rcpf(fmaxf(sqf(nv), 1e-12f));
  frow[lane] = v;
  nrow[lane] = f2bf(v * r);
}

// ---------------- prep: convert E/R to bf16 tables + pack both W1 ----------
__global__ __launch_bounds__(256) void prep_kernel(
    const float* __restrict__ E, const float* __restrict__ R,
    const float* __restrict__ w1_ed, const float* __restrict__ w1_hy,
    ushort* __restrict__ Ebf, ushort* __restrict__ Rbf,
    ushort* __restrict__ w1p_ed, ushort* __restrict__ w1p_hy) {
  int blk = blockIdx.x, tid = threadIdx.x;
  if (blk < NCONVBLK) {
    int u = blk * 256 + tid;
    if (u >= NCONV4) return;
    const float* src;
    ushort* dst;
    if (u < NE * ND / 4) {
      src = E + (size_t)u * 4;
      dst = Ebf + (size_t)u * 4;
    } else {
      int v = u - NE * ND / 4;
      src = R + (size_t)v * 4;
      dst = Rbf + (size_t)v * 4;
    }
    float4 v4 = *(const float4*)src;
    uint lo = pack_bf2(v4.x, v4.y);
    uint hi = pack_bf2(v4.z, v4.w);
    uint2 o; o.x = lo; o.y = hi;
    *(uint2*)dst = o;
  } else {
    int e = (blk - NCONVBLK) * 256 + tid;   // 0..16383
    const float* w1 = (e < 8192) ? w1_ed : w1_hy;
    ushort* out = (e < 8192) ? w1p_ed : w1p_hy;
    e &= 8191;
    int j = e & 7, ln = (e >> 3) & 63, nt = (e >> 9) & 3, kt = e >> 11;
    int n = nt * 16 + (ln & 15), k = kt * 32 + ((ln >> 4) << 3) + j;
    out[e] = f2bf(w1[k * 64 + n]);
  }
}

// ---------------- ALL-FAMILY agg kernel (b = blockIdx.x for XCD locality) ----
constexpr int OFF_H = 0;
constexpr int OFF_P = 4608;
constexpr int OFF_T = 9728;
constexpr int XS = 152;
constexpr int REGA_SZ = 14336;   // 28672 B

__global__ __launch_bounds__(256) void agg_all_kernel(
    const ushort* __restrict__ Ebf, const ushort* __restrict__ Rbf,
    const int* __restrict__ items,
    const int* __restrict__ h0, const int* __restrict__ r0, const int* __restrict__ t0,
    const int* __restrict__ h1, const int* __restrict__ r1, const int* __restrict__ t1,
    const int* __restrict__ h2, const int* __restrict__ r2, const int* __restrict__ t2,
    const int* __restrict__ h3, const int* __restrict__ r3, const int* __restrict__ t3,
    const ushort* __restrict__ w1p_ed, const float* __restrict__ w2_ed,
    const ushort* __restrict__ w1p_hy, const float* __restrict__ b1,
    const float* __restrict__ w2_hy, const float* __restrict__ b2,
    const float* __restrict__ curv,
    float* __restrict__ stacks, ushort* __restrict__ nbf) {
  __shared__ __align__(16) ushort regA[REGA_SZ];
  __shared__ float a_s[64];
  __shared__ float part[4][64];
  __shared__ float minit[4][64];

  const int b = blockIdx.x;
  const int fam = blockIdx.y;
  const int tid = threadIdx.x;
  const int wave = tid >> 6, lane = tid & 63;
  const int m0 = __builtin_amdgcn_readfirstlane(wave) * 16;
  const int colq = lane & 15, quad = lane >> 4;
  const size_t L = (size_t)NB * ND;

  const int* h_idx = (fam == 0) ? h0 : (fam == 1) ? h1 : (fam == 2) ? h2 : h3;
  const int* r_idx = (fam == 0) ? r0 : (fam == 1) ? r1 : (fam == 2) ? r2 : r3;
  const int* t_idx = (fam == 0) ? t0 : (fam == 1) ? t1 : (fam == 2) ? t2 : t3;
  float* sb = stacks + (size_t)fam * STACK;
  ushort* nb = nbf + (size_t)fam * STACK;

  uint hp[16];   // packed bf16 (h low | p high), carried across layers

  if (fam < 2) {
    // ======================= Euclidean path =======================
    const int do_init = (fam == 0);
    for (int layer = 0; layer < 2; ++layer) {
      float tv[16];
      if (layer == 0) {
        // fam==1 (ikg): init row = E[items[b]]
        if (!do_init && wave == 0) {
          float v = bf2f(Ebf[(size_t)items[b] * ND + lane]);
          write_row_norm(v, sb + (size_t)b * ND, nb + (size_t)b * ND, lane);
        }
        float macc = 0.f;
#pragma unroll
        for (int mi = 0; mi < 16; ++mi) {
          const int m = m0 + mi;
          ushort hb = Ebf[(size_t)h_idx[b * NM + m] * ND + lane];
          ushort pb = Rbf[(size_t)r_idx[b * NM + m] * ND + lane];
          if (do_init) macc += bf2f(hb);
          hp[mi] = (uint)hb | ((uint)pb << 16);
          regA[m * XS + lane] = hb;
          regA[m * XS + 64 + lane] = pb;
        }
        if (do_init) minit[wave][lane] = macc;
      } else {
#pragma unroll
        for (int mi = 0; mi < 16; ++mi) {
          const int m = m0 + mi;
          float hd = hp_lo(hp[mi]) + bf2f(Ebf[(size_t)h_idx[NBM + b * NM + m] * ND + lane]);
          float pd = hp_hi(hp[mi]) * bf2f(Rbf[(size_t)r_idx[NBM + b * NM + m] * ND + lane]);
          uint pk = pack_bf2(hd, pd);
          hp[mi] = pk;
          regA[m * XS + lane] = (ushort)pk;
          regA[m * XS + 64 + lane] = (ushort)(pk >> 16);
        }
      }
      // prefetch t rows (latency overlapped with MLP MFMAs)
#pragma unroll
      for (int mi = 0; mi < 16; ++mi)
        tv[mi] = bf2f(Ebf[(size_t)t_idx[(size_t)layer * NBM + b * NM + m0 + mi] * ND + lane]);

      // MLP on own xt rows
      {
        short8 afr[4];
#pragma unroll
        for (int kt = 0; kt < 4; ++kt)
          afr[kt] = *(const short8*)&regA[(m0 + colq) * XS + kt * 32 + quad * 8];
        float w2v[4];
#pragma unroll
        for (int nt = 0; nt < 4; ++nt) w2v[nt] = w2_ed[nt * 16 + colq];
        float cc[4][4];
#pragma unroll
        for (int nt = 0; nt < 4; ++nt) {
          float4v c = {0.f, 0.f, 0.f, 0.f};
#pragma unroll
          for (int kt = 0; kt < 4; ++kt) {
            short8 bfr = *(const short8*)&w1p_ed[(((kt << 2) | nt) * 64 + lane) * 8];
            c = __builtin_amdgcn_mfma_f32_16x16x32_bf16(afr[kt], bfr, c, 0, 0, 0);
          }
#pragma unroll
          for (int i = 0; i < 4; ++i) cc[nt][i] = c[i];
        }
        float sred[4];
#pragma unroll
        for (int i = 0; i < 4; ++i)
          sred[i] = fmaxf(cc[0][i], 0.f) * w2v[0] + fmaxf(cc[1][i], 0.f) * w2v[1] +
                    fmaxf(cc[2][i], 0.f) * w2v[2] + fmaxf(cc[3][i], 0.f) * w2v[3];
#pragma unroll
        for (int o = 8; o > 0; o >>= 1) {
#pragma unroll
          for (int i = 0; i < 4; ++i) sred[i] += __shfl_xor(sred[i], o, 64);
        }
        if (colq == 0) {
#pragma unroll
          for (int i = 0; i < 4; ++i)
            a_s[m0 + quad * 4 + i] = 1.f / (1.f + __expf(-sred[i]));
        }
      }
      __syncthreads();   // B1: a_s ready (+ minit on layer 0)

      // redundant softmax in every wave (w for m = lane)
      float wl;
      {
        float v = a_s[lane];
        float mx = wmax(v);
        float e = __expf(v - mx);
        wl = e / wsum(e);
      }
      if (layer == 0 && do_init && wave == 0) {
        float v = (minit[0][lane] + minit[1][lane] + minit[2][lane] + minit[3][lane]) * (1.f / 64.f);
        write_row_norm(v, sb + (size_t)b * ND, nb + (size_t)b * ND, lane);
      }

      float o = 0.f;
#pragma unroll
      for (int mi = 0; mi < 16; ++mi)
        o = fmaf(readlane_f(wl, m0 + mi), tv[mi], o);
      part[wave][lane] = o;
      __syncthreads();   // B2: part ready (also guards xt/a_s for next layer)
      if (wave == 0) {
        float v = part[0][lane] + part[1][lane] + part[2][lane] + part[3][lane];
        write_row_norm(v, sb + (layer + 1) * L + (size_t)b * ND,
                       nb + (layer + 1) * L + (size_t)b * ND, lane);
      }
    }
  } else {
    // ======================= Hyperbolic path =======================
    const float cabs = fabsf(*curv);
    const int j = colq;
    const int srcl = ((j >> 2) << 4) + j;   // shuffle source for diag of m0+j

    for (int layer = 0; layer < 2; ++layer) {
      // ---- P0: gather + stage H/P/T (own rows) ----
      if (layer == 0) {
        float macc = 0.f;
#pragma unroll
        for (int mi = 0; mi < 16; ++mi) {
          const int m = m0 + mi;
          ushort hb = Ebf[(size_t)h_idx[b * NM + m] * ND + lane];
          ushort pb = Rbf[(size_t)r_idx[b * NM + m] * ND + lane];
          ushort tb = Ebf[(size_t)t_idx[b * NM + m] * ND + lane];
          macc += bf2f(hb);
          hp[mi] = (uint)hb | ((uint)pb << 16);
          regA[OFF_H + m * 72 + lane] = hb;
          regA[OFF_P + m * 72 + lane] = pb;
          regA[OFF_T + m * 72 + lane] = tb;
        }
        part[wave][lane] = macc;
      } else {
#pragma unroll
        for (int mi = 0; mi < 16; ++mi) {
          const int m = m0 + mi;
          float hd = hp_lo(hp[mi]) + bf2f(Ebf[(size_t)h_idx[NBM + b * NM + m] * ND + lane]);
          float pd = hp_hi(hp[mi]) * bf2f(Rbf[(size_t)r_idx[NBM + b * NM + m] * ND + lane]);
          ushort tb = Ebf[(size_t)t_idx[(size_t)NBM + b * NM + m] * ND + lane];
          uint pk = pack_bf2(hd, pd);
          hp[mi] = pk;
          regA[OFF_H + m * 72 + lane] = (ushort)pk;
          regA[OFF_P + m * 72 + lane] = (ushort)(pk >> 16);
          regA[OFF_T + m * 72 + lane] = tb;
        }
      }

      // ---- P1: 5 dot families via MFMA diagonals (own rows) + shuffle ----
      float sh, sp, st, sht, shp;
      {
        const int fr = m0 + colq;
        const ushort* pH = &regA[OFF_H + fr * 72 + quad * 8];
        const ushort* pP = &regA[OFF_P + fr * 72 + quad * 8];
        const ushort* pT = &regA[OFF_T + fr * 72 + quad * 8];
        short8 hh0 = *(const short8*)pH, hh1 = *(const short8*)(pH + 32);
        short8 pp0 = *(const short8*)pP, pp1 = *(const short8*)(pP + 32);
        short8 tt0 = *(const short8*)pT, tt1 = *(const short8*)(pT + 32);
        const int dr = colq & 3;
#define DIAG_DOT(OUTV, A0, A1, B0, B1)                                      \
        {                                                                    \
          float4v c = {0.f, 0.f, 0.f, 0.f};                                  \
          c = __builtin_amdgcn_mfma_f32_16x16x32_bf16(A0, B0, c, 0, 0, 0);   \
          c = __builtin_amdgcn_mfma_f32_16x16x32_bf16(A1, B1, c, 0, 0, 0);   \
          float dv = (dr & 2) ? ((dr & 1) ? c[3] : c[2])                     \
                              : ((dr & 1) ? c[1] : c[0]);                    \
          OUTV = __shfl(dv, srcl, 64);                                       \
        }
        DIAG_DOT(sh, hh0, hh1, hh0, hh1)
        DIAG_DOT(sp, pp0, pp1, pp0, pp1)
        DIAG_DOT(st, tt0, tt1, tt0, tt1)
        DIAG_DOT(sht, hh0, hh1, tt0, tt1)
        DIAG_DOT(shp, hh0, hh1, pp0, pp1)
#undef DIAG_DOT
      }

      // ---- P2: geometry for own m = m0+j (duplicated across quads) ----
      float g_ch, g_e1, g_e2, g_gh, g_q1, g_q2, g_hts2;
      {
        float rih = rcpf(fmaxf(sqf(sh), 1e-12f));
        float rip = rcpf(fmaxf(sqf(sp), 1e-12f));
        float rit = rcpf(fmaxf(sqf(st), 1e-12f));
        float nh = sqf(fmaxf(sh * rih * rih, 1e-15f));
        float ch = fast_tanh(nh) * rcpf(nh) * rih * cabs;   // hh = ch*h_raw
        float p2 = ch * ch * sh;
        float lam = 2.f * rcpf(fmaxf(1.f - p2, 1e-15f));
        float ntn = sqf(fmaxf(st * rit * rit, 1e-15f));
        float ct = fast_tanh(0.5f * lam * ntn) * rcpf(ntn) * rit;
        float y2 = ct * ct * st, xy = ch * ct * sht;
        float At = 1.f + 2.f * xy + y2, Bt = 1.f - p2;
        float rdt = rcpf(fmaxf(1.f + 2.f * xy + p2 * y2, 1e-15f));
        g_e1 = At * ch * rdt;
        g_e2 = Bt * ct * rdt;
        g_hts2 = g_e1 * g_e1 * sh + 2.f * g_e1 * g_e2 * sht + g_e2 * g_e2 * st;
        float npn = sqf(fmaxf(sp * rip * rip, 1e-15f));
        float cp = fast_tanh(0.5f * lam * npn) * rcpf(npn) * rip;
        float z2 = cp * cp * sp, xz = ch * cp * shp;
        float Ar = 1.f + 2.f * xz + z2;
        float rdr = rcpf(fmaxf(1.f + 2.f * xz + p2 * z2, 1e-15f));
        float f1 = Ar * ch * rdr, f2 = Bt * cp * rdr;       // hr = f1*h + f2*p
        float hr2 = f1 * f1 * sh + 2.f * f1 * f2 * shp + f2 * f2 * sp;
        float n128 = sqf(fmaxf(p2 + hr2, 1e-15f));
        float fq = artanh_clip(n128) * rcpf(n128);
        g_ch = ch;
        g_gh = fq * ch;
        g_q1 = fq * f1;
        g_q2 = fq * f2;
      }

      __syncthreads();   // A: all P1 reads of H/P done before xt overwrite
      if (layer == 0 && wave == 0) {
        float v = (part[0][lane] + part[1][lane] + part[2][lane] + part[3][lane]) * (1.f / 64.f);
        write_row_norm(v, sb + (size_t)b * ND, nb + (size_t)b * ND, lane);
      }

      // ---- P3: write tang rows (xt over H/P) + Hts (over T, in-lane) ----
#pragma unroll
      for (int mi = 0; mi < 16; ++mi) {
        const int m = m0 + mi;
        float hvf = hp_lo(hp[mi]);
        float pvf = hp_hi(hp[mi]);
        float tvf = bf2f(regA[OFF_T + m * 72 + lane]);
        float ghm = readlane_f(g_gh, mi);
        float q1m = readlane_f(g_q1, mi);
        float q2m = readlane_f(g_q2, mi);
        float e1m = readlane_f(g_e1, mi);
        float e2m = readlane_f(g_e2, mi);
        regA[m * XS + lane] = f2bf(ghm * hvf);
        regA[m * XS + 64 + lane] = f2bf(q1m * hvf + q2m * pvf);
        regA[OFF_T + m * 72 + lane] = f2bf(e1m * hvf + e2m * tvf);
      }

      // ---- P4: MFMA attention MLP on own xt rows ----
      {
        short8 afr[4];
#pragma unroll
        for (int kt = 0; kt < 4; ++kt)
          afr[kt] = *(const short8*)&regA[(m0 + colq) * XS + kt * 32 + quad * 8];
        float b1v[4], w2v[4];
#pragma unroll
        for (int nt = 0; nt < 4; ++nt) {
          b1v[nt] = b1[nt * 16 + colq];
          w2v[nt] = w2_hy[nt * 16 + colq];
        }
        float cc[4][4];
#pragma unroll
        for (int nt = 0; nt < 4; ++nt) {
          float4v c = {0.f, 0.f, 0.f, 0.f};
#pragma unroll
          for (int kt = 0; kt < 4; ++kt) {
            short8 bfr = *(const short8*)&w1p_hy[(((kt << 2) | nt) * 64 + lane) * 8];
            c = __builtin_amdgcn_mfma_f32_16x16x32_bf16(afr[kt], bfr, c, 0, 0, 0);
          }
#pragma unroll
          for (int i = 0; i < 4; ++i) cc[nt][i] = c[i];
        }
        float b2v = b2[0];
        float sred[4];
#pragma unroll
        for (int i = 0; i < 4; ++i)
          sred[i] = fmaxf(cc[0][i] + b1v[0], 0.f) * w2v[0] +
                    fmaxf(cc[1][i] + b1v[1], 0.f) * w2v[1] +
                    fmaxf(cc[2][i] + b1v[2], 0.f) * w2v[2] +
                    fmaxf(cc[3][i] + b1v[3], 0.f) * w2v[3];
#pragma unroll
        for (int o = 8; o > 0; o >>= 1) {
#pragma unroll
          for (int i = 0; i < 4; ++i) sred[i] += __shfl_xor(sred[i], o, 64);
        }
        if (colq == 0) {
#pragma unroll
          for (int i = 0; i < 4; ++i)
            a_s[m0 + quad * 4 + i] = fast_tanh(sred[i] + b2v);
        }
      }
      __syncthreads();   // C: a_s ready

      // redundant softmax in every wave (w for m = lane)
      float wl;
      {
        float v = a_s[lane];
        float mx = wmax(v);
        float e = __expf(v - mx);
        wl = e / wsum(e);
      }

      // ---- P5: mean_pt partials ----
      float mp = 0.f;
#pragma unroll
      for (int mi = 0; mi < 16; ++mi)
        mp = fmaf(readlane_f(wl, m0 + mi) * readlane_f(g_ch, mi), hp_lo(hp[mi]), mp);
      part[wave][lane] = mp;
      __syncthreads();   // E: partials ready

      // redundant mean-pt reduce in every wave (meanpt in lane=dim)
      float mv = part[0][lane] + part[1][lane] + part[2][lane] + part[3][lane];
      float p2m = wsum(mv * mv);

      // ---- P6: dp[m] = meanpt . ht[m] via MFMA (own Hts rows) + shuffle ----
      float dpv;
      {
        const ushort* pA = &regA[OFF_T + (m0 + colq) * 72 + quad * 8];
        short8 a0 = *(const short8*)pA, a1 = *(const short8*)(pA + 32);
        short8 bm0, bm1;
#pragma unroll
        for (int jj = 0; jj < 8; ++jj) {
          bm0[jj] = (short)f2bf(__shfl(mv, quad * 8 + jj, 64));
          bm1[jj] = (short)f2bf(__shfl(mv, 32 + quad * 8 + jj, 64));
        }
        float4v c = {0.f, 0.f, 0.f, 0.f};
        c = __builtin_amdgcn_mfma_f32_16x16x32_bf16(a0, bm0, c, 0, 0, 0);
        c = __builtin_amdgcn_mfma_f32_16x16x32_bf16(a1, bm1, c, 0, 0, 0);
        const int dr = colq & 3;
        float dv = (dr & 2) ? ((dr & 1) ? c[3] : c[2]) : ((dr & 1) ? c[1] : c[0]);
        dpv = __shfl(dv, srcl, 64);
      }

      // ---- P7: logmap scalars for own m = m0+j, per-wave accumulation ----
      const float be = fmaxf(1.f - p2m, 1e-15f);
      float g1, g2;
      {
        float wm = __shfl(wl, m0 + j, 64);
        float y2 = wm * wm * g_hts2;
        float xy = -wm * dpv;
        float al = 1.f + 2.f * xy + y2;
        float rd = rcpf(fmaxf(1.f + 2.f * xy + p2m * y2, 1e-15f));
        float md2 = (al * al * p2m - 2.f * al * be * wm * dpv + be * be * y2) * rd * rd;
        float n = sqf(fmaxf(md2, 1e-15f));
        float sm = be * artanh_clip(n) * rcpf(n) * rd;
        g1 = wm * wm * sm * be;
        g2 = wm * sm * al;
      }
      float ovec = 0.f, cA = 0.f;
#pragma unroll
      for (int mi = 0; mi < 16; ++mi) {
        const int m = m0 + mi;
        float htf = bf2f(regA[OFF_T + m * 72 + lane]);
        ovec = fmaf(readlane_f(g1, mi), htf, ovec);
        cA += readlane_f(g2, mi);
      }
      part[wave][lane] = ovec - cA * mv;
      __syncthreads();   // H: part ready (also guards regions for next layer)
      if (wave == 0) {
        float v = part[0][lane] + part[1][lane] + part[2][lane] + part[3][lane];
        write_row_norm(v, sb + (layer + 1) * L + (size_t)b * ND,
                       nb + (layer + 1) * L + (size_t)b * ND, lane);
      }
    }
  }
}

// ---------------- pos dots (from normalized nbf) + scores (from stacks) ----
__global__ __launch_bounds__(256) void pos_scores_kernel(
    const ushort* __restrict__ nbf, const float* __restrict__ stacks,
    float* __restrict__ pos, float* __restrict__ out) {
  int lane = threadIdx.x & 63;
  int wave = threadIdx.x >> 6;
  if (blockIdx.y < 2) {
    int row = blockIdx.x * 4 + wave;
    int sa = blockIdx.y;
    float a = bf2f(nbf[(size_t)sa * STACK + (size_t)row * ND + lane]);
    float c = bf2f(nbf[(size_t)(sa + 2) * STACK + (size_t)row * ND + lane]);
    float d = wsum(a * c);
    if (lane == 0) pos[sa * NROWS + row] = d;
  } else {
    int b = blockIdx.x * 4 + wave;
    if (b >= NB) return;
    float s = 0.f;
#pragma unroll
    for (int l = 0; l < 3; ++l) {
      size_t o = (size_t)l * NB * ND + (size_t)b * ND + lane;
      s += stacks[0 * (size_t)STACK + o] * stacks[3 * (size_t)STACK + o]
         + stacks[2 * (size_t)STACK + o] * stacks[1 * (size_t)STACK + o];
    }
    s = wsum(s);
    if (lane == 0) out[b] = 1.f / (1.f + __expf(-s));
  }
}

// ---------------- contrastive denominators via MFMA, LDS-staged Y ----------------
__global__ __launch_bounds__(256) void lse_mfma_kernel(
    const ushort* __restrict__ nbf, float* __restrict__ Spart) {
  __shared__ __align__(16) ushort ytile[2][64 * 72];   // 36 KB
  const int tid = threadIdx.x;
  const int wave = tid >> 6, lane = tid & 63;
  const int pair = blockIdx.y;
  const int z = blockIdx.z;
  int xi = (pair & 2) ? ((pair & 1) ? 3 : 1) : ((pair & 1) ? 2 : 0);
  int yi = xi ^ 2;
  const ushort* X = nbf + (size_t)xi * STACK;
  const ushort* Y = nbf + (size_t)yi * STACK;
  const int r0 = blockIdx.x * 64 + wave * 16;
  const int row = lane & 15, quad = lane >> 4;

  short8 a0 = *(const short8*)&X[(size_t)(r0 + row) * 64 + quad * 8];
  short8 a1 = *(const short8*)&X[(size_t)(r0 + row) * 64 + 32 + quad * 8];

  const int srow = tid >> 2, schunk = tid & 3;
  constexpr int NT = (NROWS / NZ) / 64;   // 12 tiles
  const int c0 = z * (NROWS / NZ);
  const ushort* sg = &Y[(size_t)(c0 + srow) * 64 + schunk * 16];
  ushort* sl = &ytile[0][0] + srow * 72 + schunk * 16;

  {
    short8 s0 = *(const short8*)sg;
    short8 s1 = *(const short8*)(sg + 8);
    *(short8*)sl = s0;
    *(short8*)(sl + 8) = s1;
  }
  __syncthreads();

  float rsum[4] = {0.f, 0.f, 0.f, 0.f};
  for (int ct = 0; ct < NT; ++ct) {
    const int cur = ct & 1;
    short8 n0, n1;
    if (ct + 1 < NT) {
      const ushort* src = sg + (size_t)(ct + 1) * 64 * 64;
      n0 = *(const short8*)src;
      n1 = *(const short8*)(src + 8);
    }
#pragma unroll
    for (int nt = 0; nt < 4; ++nt) {
      const ushort* yr = &ytile[cur][(nt * 16 + row) * 72 + quad * 8];
      short8 b0 = *(const short8*)yr;
      short8 b1 = *(const short8*)(yr + 32);
      float4v c = {0.f, 0.f, 0.f, 0.f};
      c = __builtin_amdgcn_mfma_f32_16x16x32_bf16(a0, b0, c, 0, 0, 0);
      c = __builtin_amdgcn_mfma_f32_16x16x32_bf16(a1, b1, c, 0, 0, 0);
#pragma unroll
      for (int i = 0; i < 4; ++i) rsum[i] += __expf(c[i] * 5.f);
    }
    if (ct + 1 < NT) {
      ushort* dst = &ytile[0][0] + ((ct + 1) & 1) * (64 * 72) + srow * 72 + schunk * 16;
      *(short8*)dst = n0;
      *(short8*)(dst + 8) = n1;
      __syncthreads();
    }
  }
#pragma unroll
  for (int i = 0; i < 4; ++i) {
    float v = rsum[i];
    v += __shfl_xor(v, 1, 64);
    v += __shfl_xor(v, 2, 64);
    v += __shfl_xor(v, 4, 64);
    v += __shfl_xor(v, 8, 64);
    if (row == 0)
      Spart[((size_t)z * 4 + pair) * NROWS + r0 + quad * 4 + i] = v;
  }
}

// ---------------- loss: grid-parallel partials + final reduce ----------------
__global__ __launch_bounds__(256) void loss_part_kernel(
    const float* __restrict__ Spart, const float* __restrict__ pos,
    double* __restrict__ lossp) {
  __shared__ double red[256];
  const int t = threadIdx.x, blk = blockIdx.x;
  double acc = 0.0;
#pragma unroll
  for (int r = 0; r < 2; ++r) {
    int i = blk * 512 + r * 256 + t;   // i in [0, 4*NROWS)
    float s = 0.f;
#pragma unroll
    for (int zz = 0; zz < NZ; ++zz) s += Spart[i + zz * 4 * NROWS];
    acc += (double)__logf(s);
  }
  {
    int jj = blk * 256 + t;            // j in [0, 2*NROWS)
    acc -= 10.0 * (double)pos[jj];
  }
  red[t] = acc;
  __syncthreads();
  for (int s = 128; s > 0; s >>= 1) {
    if (t < s) red[t] += red[t + s];
    __syncthreads();
  }
  if (t == 0) lossp[blk] = red[0];
}

__global__ __launch_bounds__(64) void loss_final_kernel(
    const double* __restrict__ lossp, float* __restrict__ out) {
  int lane = threadIdx.x;
  double v = (lane < 48) ? lossp[lane] : 0.0;
#pragma unroll
  for (int o = 32; o > 0; o >>= 1) v += __shfl_xor(v, o, 64);
  if (lane == 0) out[NB] = (float)(1e-6 * v);
}

extern "C" void kernel_launch(void* const* d_in, const int* in_sizes, int n_in,
                              void* d_out, int out_size, void* d_ws, size_t ws_size,
                              hipStream_t stream) {
  const int* items = (const int*)d_in[0];
  const int* ucf_h = (const int*)d_in[1];
  const int* ucf_r = (const int*)d_in[2];
  const int* ucf_t = (const int*)d_in[3];
  const int* ikg_h = (const int*)d_in[4];
  const int* ikg_r = (const int*)d_in[5];
  const int* ikg_t = (const int*)d_in[6];
  const int* ukg_h = (const int*)d_in[7];
  const int* ukg_r = (const int*)d_in[8];
  const int* ukg_t = (const int*)d_in[9];
  const int* icf_h = (const int*)d_in[10];
  const int* icf_r = (const int*)d_in[11];
  const int* icf_t = (const int*)d_in[12];
  const float* E = (const float*)d_in[13];
  const float* R = (const float*)d_in[14];
  const float* att_w1 = (const float*)d_in[15];
  const float* att_w2 = (const float*)d_in[16];
  const float* a2_w1 = (const float*)d_in[17];
  const float* a2_b1 = (const float*)d_in[18];
  const float* a2_w2 = (const float*)d_in[19];
  const float* a2_b2 = (const float*)d_in[20];
  const float* curv = (const float*)d_in[21];
  float* outp = (float*)d_out;

  float* ws = (float*)d_ws;
  float* stacks = ws;                                    // 4*STACK f32
  float* Spart = stacks + 4 * (size_t)STACK;             // NZ*4*NROWS f32
  float* posarr = Spart + (size_t)NZ * 4 * NROWS;        // 2*NROWS f32
  ushort* nbf = (ushort*)(posarr + 2 * (size_t)NROWS);   // 4*STACK bf16
  ushort* w1p_ed = nbf + 4 * (size_t)STACK;              // 8192 ushort
  ushort* w1p_hy = w1p_ed + 8192;                        // 8192 ushort
  ushort* Ebf = w1p_hy + 8192;                           // NE*ND ushort (12.8 MB)
  ushort* Rbf = Ebf + (size_t)NE * ND;                   // NR*ND ushort
  double* lossp = (double*)(Rbf + (size_t)NR * ND);      // 48 doubles

  prep_kernel<<<NCONVBLK + NW1BLK, 256, 0, stream>>>(
      E, R, att_w1, a2_w1, Ebf, Rbf, w1p_ed, w1p_hy);

  agg_all_kernel<<<dim3(NB, 4), 256, 0, stream>>>(
      Ebf, Rbf, items,
      ucf_h, ucf_r, ucf_t, ikg_h, ikg_r, ikg_t,
      ukg_h, ukg_r, ukg_t, icf_h, icf_r, icf_t,
      w1p_ed, att_w2, w1p_hy, a2_b1, a2_w2, a2_b2, curv,
      stacks, nbf);

  pos_scores_kernel<<<dim3(NROWS / 4, 3), 256, 0, stream>>>(nbf, stacks, posarr, outp);
  lse_mfma_kernel<<<dim3(NROWS / 64, 4, NZ), 256, 0, stream>>>(nbf, Spart);

  loss_part_kernel<<<48, 256, 0, stream>>>(Spart, posarr, lossp);
  loss_final_kernel<<<1, 64, 0, stream>>>(lossp, outp);
}

// Round 17
// 342.418 us; speedup vs baseline: 1.0350x; 1.0350x over previous
//
#include <hip/hip_runtime.h>
#include <hip/hip_bf16.h>
#include <cstdint>
#include <cstddef>

// Problem constants (match reference)
constexpr int NB = 2048;            // batch
constexpr int NM = 64;              // neighbors M
constexpr int ND = 64;              // dim
constexpr int NBM = NB * NM;        // 131072 (one layer of an index tensor)
constexpr int NROWS = 3 * NB;       // 6144 rows per stack (L+1 = 3)
constexpr int STACK = 3 * NB * ND;  // 393216 floats per stack
constexpr int NZ = 8;               // lse column splits

typedef __attribute__((ext_vector_type(8))) short short8;
typedef __attribute__((ext_vector_type(4))) float float4v;

__device__ __forceinline__ float wsum(float v) {
#pragma unroll
  for (int o = 32; o > 0; o >>= 1) v += __shfl_xor(v, o, 64);
  return v;
}

__device__ __forceinline__ float wmax(float v) {
#pragma unroll
  for (int o = 32; o > 0; o >>= 1) v = fmaxf(v, __shfl_xor(v, o, 64));
  return v;
}

__device__ __forceinline__ float rcpf(float x) { return __builtin_amdgcn_rcpf(x); }
__device__ __forceinline__ float sqf(float x) { return __builtin_amdgcn_sqrtf(x); }

__device__ __forceinline__ float fast_tanh(float x) {
  float t = __expf(2.f * x);
  return (t - 1.f) * rcpf(t + 1.f);
}

// artanh(clip(x, -1+1e-5, 1-1e-5))
__device__ __forceinline__ float artanh_clip(float x) {
  x = fminf(fmaxf(x, -1.f + 1e-5f), 1.f - 1e-5f);
  return 0.5f * __logf((1.f + x) * rcpf(1.f - x));
}

// fp32 -> bf16 round-half-up (error <= 0.5 ulp; 2 VALU ops)
__device__ __forceinline__ ushort f2bf(float f) {
  return (ushort)((__float_as_uint(f) + 0x8000u) >> 16);
}
__device__ __forceinline__ float bf2f(ushort u) {
  return __uint_as_float((uint)u << 16);
}
// pack two floats as bf16 pair (h in low, p in high)
__device__ __forceinline__ uint pack_bf2(float h, float p) {
  uint hu = __float_as_uint(h) + 0x8000u;
  uint pu = __float_as_uint(p) + 0x8000u;
  return __builtin_amdgcn_perm(pu, hu, 0x07060302);
}
__device__ __forceinline__ float hp_lo(uint v) { return __uint_as_float(v << 16); }
__device__ __forceinline__ float hp_hi(uint v) { return __uint_as_float(v & 0xFFFF0000u); }

// broadcast a float from lane l (wave-uniform l)
__device__ __forceinline__ float readlane_f(float v, int l) {
  return __int_as_float(__builtin_amdgcn_readlane(__float_as_int(v), l));
}

// normalized bf16 write of a full row held lane=dim (call from one wave)
__device__ __forceinline__ void write_row_norm(
    float v, float* __restrict__ frow, ushort* __restrict__ nrow, int lane) {
  float nv = wsum(v * v);
  float r = rcpf(fmaxf(sqf(nv), 1e-12f));
  frow[lane] = v;
  nrow[lane] = f2bf(v * r);
}

// ---------------- prep: pack both W1 into MFMA B-frag layout ----------------
__global__ __launch_bounds__(64) void prep_kernel(
    const float* __restrict__ w1_ed, const float* __restrict__ w1_hy,
    ushort* __restrict__ w1p_ed, ushort* __restrict__ w1p_hy) {
  int e = blockIdx.x * 64 + threadIdx.x;    // 0..16383
  const float* w1 = (e < 8192) ? w1_ed : w1_hy;
  ushort* out = (e < 8192) ? w1p_ed : w1p_hy;
  e &= 8191;
  int j = e & 7, ln = (e >> 3) & 63, nt = (e >> 9) & 3, kt = e >> 11;
  int n = nt * 16 + (ln & 15), k = kt * 32 + ((ln >> 4) << 3) + j;
  out[e] = f2bf(w1[k * 64 + n]);
}

// ---------------- ALL-FAMILY agg kernel (b = blockIdx.x for XCD locality) ----
constexpr int OFF_H = 0;
constexpr int OFF_P = 4608;
constexpr int OFF_T = 9728;
constexpr int XS = 152;
constexpr int REGA_SZ = 14336;   // 28672 B

__global__ __launch_bounds__(256) void agg_all_kernel(
    const float* __restrict__ E, const float* __restrict__ R,
    const int* __restrict__ items,
    const int* __restrict__ h0, const int* __restrict__ r0, const int* __restrict__ t0,
    const int* __restrict__ h1, const int* __restrict__ r1, const int* __restrict__ t1,
    const int* __restrict__ h2, const int* __restrict__ r2, const int* __restrict__ t2,
    const int* __restrict__ h3, const int* __restrict__ r3, const int* __restrict__ t3,
    const ushort* __restrict__ w1p_ed, const float* __restrict__ w2_ed,
    const ushort* __restrict__ w1p_hy, const float* __restrict__ b1,
    const float* __restrict__ w2_hy, const float* __restrict__ b2,
    const float* __restrict__ curv,
    float* __restrict__ stacks, ushort* __restrict__ nbf) {
  __shared__ __align__(16) ushort regA[REGA_SZ];
  __shared__ float a_s[64];
  __shared__ float part[4][64];
  __shared__ float minit[4][64];

  const int b = blockIdx.x;
  const int fam = blockIdx.y;
  const int tid = threadIdx.x;
  const int wave = tid >> 6, lane = tid & 63;
  const int m0 = __builtin_amdgcn_readfirstlane(wave) * 16;
  const int colq = lane & 15, quad = lane >> 4;
  const size_t L = (size_t)NB * ND;

  const int* h_idx = (fam == 0) ? h0 : (fam == 1) ? h1 : (fam == 2) ? h2 : h3;
  const int* r_idx = (fam == 0) ? r0 : (fam == 1) ? r1 : (fam == 2) ? r2 : r3;
  const int* t_idx = (fam == 0) ? t0 : (fam == 1) ? t1 : (fam == 2) ? t2 : t3;
  float* sb = stacks + (size_t)fam * STACK;
  ushort* nb = nbf + (size_t)fam * STACK;

  uint hp[16];   // packed bf16 (h low | p high), carried across layers

  if (fam < 2) {
    // ======================= Euclidean path =======================
    const int do_init = (fam == 0);
    for (int layer = 0; layer < 2; ++layer) {
      float tv[16];
      if (layer == 0) {
        // fam==1 (ikg): init row = E[items[b]] (fused from old prep)
        if (!do_init && wave == 0) {
          float v = E[(size_t)items[b] * ND + lane];
          write_row_norm(v, sb + (size_t)b * ND, nb + (size_t)b * ND, lane);
        }
        float macc = 0.f;
#pragma unroll
        for (int mi = 0; mi < 16; ++mi) {
          const int m = m0 + mi;
          float hd = E[(size_t)h_idx[b * NM + m] * ND + lane];
          float pd = R[(size_t)r_idx[b * NM + m] * ND + lane];
          macc += hd;
          uint pk = pack_bf2(hd, pd);
          hp[mi] = pk;
          regA[m * XS + lane] = (ushort)pk;
          regA[m * XS + 64 + lane] = (ushort)(pk >> 16);
        }
        if (do_init) minit[wave][lane] = macc;
      } else {
#pragma unroll
        for (int mi = 0; mi < 16; ++mi) {
          const int m = m0 + mi;
          float hd = hp_lo(hp[mi]) + E[(size_t)h_idx[NBM + b * NM + m] * ND + lane];
          float pd = hp_hi(hp[mi]) * R[(size_t)r_idx[NBM + b * NM + m] * ND + lane];
          uint pk = pack_bf2(hd, pd);
          hp[mi] = pk;
          regA[m * XS + lane] = (ushort)pk;
          regA[m * XS + 64 + lane] = (ushort)(pk >> 16);
        }
      }
      // prefetch t rows (latency overlapped with MLP MFMAs)
#pragma unroll
      for (int mi = 0; mi < 16; ++mi)
        tv[mi] = E[(size_t)t_idx[(size_t)layer * NBM + b * NM + m0 + mi] * ND + lane];

      // MLP on own xt rows
      {
        short8 afr[4];
#pragma unroll
        for (int kt = 0; kt < 4; ++kt)
          afr[kt] = *(const short8*)&regA[(m0 + colq) * XS + kt * 32 + quad * 8];
        float w2v[4];
#pragma unroll
        for (int nt = 0; nt < 4; ++nt) w2v[nt] = w2_ed[nt * 16 + colq];
        float cc[4][4];
#pragma unroll
        for (int nt = 0; nt < 4; ++nt) {
          float4v c = {0.f, 0.f, 0.f, 0.f};
#pragma unroll
          for (int kt = 0; kt < 4; ++kt) {
            short8 bfr = *(const short8*)&w1p_ed[(((kt << 2) | nt) * 64 + lane) * 8];
            c = __builtin_amdgcn_mfma_f32_16x16x32_bf16(afr[kt], bfr, c, 0, 0, 0);
          }
#pragma unroll
          for (int i = 0; i < 4; ++i) cc[nt][i] = c[i];
        }
        float sred[4];
#pragma unroll
        for (int i = 0; i < 4; ++i)
          sred[i] = fmaxf(cc[0][i], 0.f) * w2v[0] + fmaxf(cc[1][i], 0.f) * w2v[1] +
                    fmaxf(cc[2][i], 0.f) * w2v[2] + fmaxf(cc[3][i], 0.f) * w2v[3];
#pragma unroll
        for (int o = 8; o > 0; o >>= 1) {
#pragma unroll
          for (int i = 0; i < 4; ++i) sred[i] += __shfl_xor(sred[i], o, 64);
        }
        if (colq == 0) {
#pragma unroll
          for (int i = 0; i < 4; ++i)
            a_s[m0 + quad * 4 + i] = 1.f / (1.f + __expf(-sred[i]));
        }
      }
      __syncthreads();   // B1: a_s ready (+ minit on layer 0)

      // redundant softmax in every wave (w for m = lane)
      float wl;
      {
        float v = a_s[lane];
        float mx = wmax(v);
        float e = __expf(v - mx);
        wl = e / wsum(e);
      }
      if (layer == 0 && do_init && wave == 0) {
        float v = (minit[0][lane] + minit[1][lane] + minit[2][lane] + minit[3][lane]) * (1.f / 64.f);
        write_row_norm(v, sb + (size_t)b * ND, nb + (size_t)b * ND, lane);
      }

      float o = 0.f;
#pragma unroll
      for (int mi = 0; mi < 16; ++mi)
        o = fmaf(readlane_f(wl, m0 + mi), tv[mi], o);
      part[wave][lane] = o;
      __syncthreads();   // B2: part ready (also guards xt/a_s for next layer)
      if (wave == 0) {
        float v = part[0][lane] + part[1][lane] + part[2][lane] + part[3][lane];
        write_row_norm(v, sb + (layer + 1) * L + (size_t)b * ND,
                       nb + (layer + 1) * L + (size_t)b * ND, lane);
      }
    }
  } else {
    // ======================= Hyperbolic path =======================
    const float cabs = fabsf(*curv);
    const int j = colq;
    const int srcl = ((j >> 2) << 4) + j;   // shuffle source for diag of m0+j

    for (int layer = 0; layer < 2; ++layer) {
      // ---- P0: gather + stage H/P/T (own rows) ----
      if (layer == 0) {
        float macc = 0.f;
#pragma unroll
        for (int mi = 0; mi < 16; ++mi) {
          const int m = m0 + mi;
          float hd = E[(size_t)h_idx[b * NM + m] * ND + lane];
          float pd = R[(size_t)r_idx[b * NM + m] * ND + lane];
          float td = E[(size_t)t_idx[b * NM + m] * ND + lane];
          macc += hd;
          uint pk = pack_bf2(hd, pd);
          hp[mi] = pk;
          regA[OFF_H + m * 72 + lane] = (ushort)pk;
          regA[OFF_P + m * 72 + lane] = (ushort)(pk >> 16);
          regA[OFF_T + m * 72 + lane] = f2bf(td);
        }
        part[wave][lane] = macc;
      } else {
#pragma unroll
        for (int mi = 0; mi < 16; ++mi) {
          const int m = m0 + mi;
          float hd = hp_lo(hp[mi]) + E[(size_t)h_idx[NBM + b * NM + m] * ND + lane];
          float pd = hp_hi(hp[mi]) * R[(size_t)r_idx[NBM + b * NM + m] * ND + lane];
          float td = E[(size_t)t_idx[(size_t)NBM + b * NM + m] * ND + lane];
          uint pk = pack_bf2(hd, pd);
          hp[mi] = pk;
          regA[OFF_H + m * 72 + lane] = (ushort)pk;
          regA[OFF_P + m * 72 + lane] = (ushort)(pk >> 16);
          regA[OFF_T + m * 72 + lane] = f2bf(td);
        }
      }

      // ---- P1: 5 dot families via MFMA diagonals (own rows) + shuffle ----
      float sh, sp, st, sht, shp;
      {
        const int fr = m0 + colq;
        const ushort* pH = &regA[OFF_H + fr * 72 + quad * 8];
        const ushort* pP = &regA[OFF_P + fr * 72 + quad * 8];
        const ushort* pT = &regA[OFF_T + fr * 72 + quad * 8];
        short8 hh0 = *(const short8*)pH, hh1 = *(const short8*)(pH + 32);
        short8 pp0 = *(const short8*)pP, pp1 = *(const short8*)(pP + 32);
        short8 tt0 = *(const short8*)pT, tt1 = *(const short8*)(pT + 32);
        const int dr = colq & 3;
#define DIAG_DOT(OUTV, A0, A1, B0, B1)                                      \
        {                                                                    \
          float4v c = {0.f, 0.f, 0.f, 0.f};                                  \
          c = __builtin_amdgcn_mfma_f32_16x16x32_bf16(A0, B0, c, 0, 0, 0);   \
          c = __builtin_amdgcn_mfma_f32_16x16x32_bf16(A1, B1, c, 0, 0, 0);   \
          float dv = (dr & 2) ? ((dr & 1) ? c[3] : c[2])                     \
                              : ((dr & 1) ? c[1] : c[0]);                    \
          OUTV = __shfl(dv, srcl, 64);                                       \
        }
        DIAG_DOT(sh, hh0, hh1, hh0, hh1)
        DIAG_DOT(sp, pp0, pp1, pp0, pp1)
        DIAG_DOT(st, tt0, tt1, tt0, tt1)
        DIAG_DOT(sht, hh0, hh1, tt0, tt1)
        DIAG_DOT(shp, hh0, hh1, pp0, pp1)
#undef DIAG_DOT
      }

      // ---- P2: geometry for own m = m0+j (duplicated across quads) ----
      float g_ch, g_e1, g_e2, g_gh, g_q1, g_q2, g_hts2;
      {
        float rih = rcpf(fmaxf(sqf(sh), 1e-12f));
        float rip = rcpf(fmaxf(sqf(sp), 1e-12f));
        float rit = rcpf(fmaxf(sqf(st), 1e-12f));
        float nh = sqf(fmaxf(sh * rih * rih, 1e-15f));
        float ch = fast_tanh(nh) * rcpf(nh) * rih * cabs;   // hh = ch*h_raw
        float p2 = ch * ch * sh;
        float lam = 2.f * rcpf(fmaxf(1.f - p2, 1e-15f));
        float ntn = sqf(fmaxf(st * rit * rit, 1e-15f));
        float ct = fast_tanh(0.5f * lam * ntn) * rcpf(ntn) * rit;
        float y2 = ct * ct * st, xy = ch * ct * sht;
        float At = 1.f + 2.f * xy + y2, Bt = 1.f - p2;
        float rdt = rcpf(fmaxf(1.f + 2.f * xy + p2 * y2, 1e-15f));
        g_e1 = At * ch * rdt;
        g_e2 = Bt * ct * rdt;
        g_hts2 = g_e1 * g_e1 * sh + 2.f * g_e1 * g_e2 * sht + g_e2 * g_e2 * st;
        float npn = sqf(fmaxf(sp * rip * rip, 1e-15f));
        float cp = fast_tanh(0.5f * lam * npn) * rcpf(npn) * rip;
        float z2 = cp * cp * sp, xz = ch * cp * shp;
        float Ar = 1.f + 2.f * xz + z2;
        float rdr = rcpf(fmaxf(1.f + 2.f * xz + p2 * z2, 1e-15f));
        float f1 = Ar * ch * rdr, f2 = Bt * cp * rdr;       // hr = f1*h + f2*p
        float hr2 = f1 * f1 * sh + 2.f * f1 * f2 * shp + f2 * f2 * sp;
        float n128 = sqf(fmaxf(p2 + hr2, 1e-15f));
        float fq = artanh_clip(n128) * rcpf(n128);
        g_ch = ch;
        g_gh = fq * ch;
        g_q1 = fq * f1;
        g_q2 = fq * f2;
      }

      __syncthreads();   // A: all P1 reads of H/P done before xt overwrite
      if (layer == 0 && wave == 0) {
        float v = (part[0][lane] + part[1][lane] + part[2][lane] + part[3][lane]) * (1.f / 64.f);
        write_row_norm(v, sb + (size_t)b * ND, nb + (size_t)b * ND, lane);
      }

      // ---- P3: write tang rows (xt over H/P) + Hts (over T, in-lane) ----
#pragma unroll
      for (int mi = 0; mi < 16; ++mi) {
        const int m = m0 + mi;
        float hvf = hp_lo(hp[mi]);
        float pvf = hp_hi(hp[mi]);
        float tvf = bf2f(regA[OFF_T + m * 72 + lane]);
        float ghm = readlane_f(g_gh, mi);
        float q1m = readlane_f(g_q1, mi);
        float q2m = readlane_f(g_q2, mi);
        float e1m = readlane_f(g_e1, mi);
        float e2m = readlane_f(g_e2, mi);
        regA[m * XS + lane] = f2bf(ghm * hvf);
        regA[m * XS + 64 + lane] = f2bf(q1m * hvf + q2m * pvf);
        regA[OFF_T + m * 72 + lane] = f2bf(e1m * hvf + e2m * tvf);
      }

      // ---- P4: MFMA attention MLP on own xt rows ----
      {
        short8 afr[4];
#pragma unroll
        for (int kt = 0; kt < 4; ++kt)
          afr[kt] = *(const short8*)&regA[(m0 + colq) * XS + kt * 32 + quad * 8];
        float b1v[4], w2v[4];
#pragma unroll
        for (int nt = 0; nt < 4; ++nt) {
          b1v[nt] = b1[nt * 16 + colq];
          w2v[nt] = w2_hy[nt * 16 + colq];
        }
        float cc[4][4];
#pragma unroll
        for (int nt = 0; nt < 4; ++nt) {
          float4v c = {0.f, 0.f, 0.f, 0.f};
#pragma unroll
          for (int kt = 0; kt < 4; ++kt) {
            short8 bfr = *(const short8*)&w1p_hy[(((kt << 2) | nt) * 64 + lane) * 8];
            c = __builtin_amdgcn_mfma_f32_16x16x32_bf16(afr[kt], bfr, c, 0, 0, 0);
          }
#pragma unroll
          for (int i = 0; i < 4; ++i) cc[nt][i] = c[i];
        }
        float b2v = b2[0];
        float sred[4];
#pragma unroll
        for (int i = 0; i < 4; ++i)
          sred[i] = fmaxf(cc[0][i] + b1v[0], 0.f) * w2v[0] +
                    fmaxf(cc[1][i] + b1v[1], 0.f) * w2v[1] +
                    fmaxf(cc[2][i] + b1v[2], 0.f) * w2v[2] +
                    fmaxf(cc[3][i] + b1v[3], 0.f) * w2v[3];
#pragma unroll
        for (int o = 8; o > 0; o >>= 1) {
#pragma unroll
          for (int i = 0; i < 4; ++i) sred[i] += __shfl_xor(sred[i], o, 64);
        }
        if (colq == 0) {
#pragma unroll
          for (int i = 0; i < 4; ++i)
            a_s[m0 + quad * 4 + i] = fast_tanh(sred[i] + b2v);
        }
      }
      __syncthreads();   // C: a_s ready

      // redundant softmax in every wave (w for m = lane)
      float wl;
      {
        float v = a_s[lane];
        float mx = wmax(v);
        float e = __expf(v - mx);
        wl = e / wsum(e);
      }

      // ---- P5: mean_pt partials ----
      float mp = 0.f;
#pragma unroll
      for (int mi = 0; mi < 16; ++mi)
        mp = fmaf(readlane_f(wl, m0 + mi) * readlane_f(g_ch, mi), hp_lo(hp[mi]), mp);
      part[wave][lane] = mp;
      __syncthreads();   // E: partials ready

      // redundant mean-pt reduce in every wave (meanpt in lane=dim)
      float mv = part[0][lane] + part[1][lane] + part[2][lane] + part[3][lane];
      float p2m = wsum(mv * mv);

      // ---- P6: dp[m] = meanpt . ht[m] via MFMA (own Hts rows) + shuffle ----
      float dpv;
      {
        const ushort* pA = &regA[OFF_T + (m0 + colq) * 72 + quad * 8];
        short8 a0 = *(const short8*)pA, a1 = *(const short8*)(pA + 32);
        short8 bm0, bm1;
#pragma unroll
        for (int jj = 0; jj < 8; ++jj) {
          bm0[jj] = (short)f2bf(__shfl(mv, quad * 8 + jj, 64));
          bm1[jj] = (short)f2bf(__shfl(mv, 32 + quad * 8 + jj, 64));
        }
        float4v c = {0.f, 0.f, 0.f, 0.f};
        c = __builtin_amdgcn_mfma_f32_16x16x32_bf16(a0, bm0, c, 0, 0, 0);
        c = __builtin_amdgcn_mfma_f32_16x16x32_bf16(a1, bm1, c, 0, 0, 0);
        const int dr = colq & 3;
        float dv = (dr & 2) ? ((dr & 1) ? c[3] : c[2]) : ((dr & 1) ? c[1] : c[0]);
        dpv = __shfl(dv, srcl, 64);
      }

      // ---- P7: logmap scalars for own m = m0+j, per-wave accumulation ----
      const float be = fmaxf(1.f - p2m, 1e-15f);
      float g1, g2;
      {
        float wm = __shfl(wl, m0 + j, 64);
        float y2 = wm * wm * g_hts2;
        float xy = -wm * dpv;
        float al = 1.f + 2.f * xy + y2;
        float rd = rcpf(fmaxf(1.f + 2.f * xy + p2m * y2, 1e-15f));
        float md2 = (al * al * p2m - 2.f * al * be * wm * dpv + be * be * y2) * rd * rd;
        float n = sqf(fmaxf(md2, 1e-15f));
        float sm = be * artanh_clip(n) * rcpf(n) * rd;
        g1 = wm * wm * sm * be;
        g2 = wm * sm * al;
      }
      float ovec = 0.f, cA = 0.f;
#pragma unroll
      for (int mi = 0; mi < 16; ++mi) {
        const int m = m0 + mi;
        float htf = bf2f(regA[OFF_T + m * 72 + lane]);
        ovec = fmaf(readlane_f(g1, mi), htf, ovec);
        cA += readlane_f(g2, mi);
      }
      part[wave][lane] = ovec - cA * mv;
      __syncthreads();   // H: part ready (also guards regions for next layer)
      if (wave == 0) {
        float v = part[0][lane] + part[1][lane] + part[2][lane] + part[3][lane];
        write_row_norm(v, sb + (layer + 1) * L + (size_t)b * ND,
                       nb + (layer + 1) * L + (size_t)b * ND, lane);
      }
    }
  }
}

// ---------------- pos dots (from normalized nbf) + scores (from stacks) ----
__global__ __launch_bounds__(256) void pos_scores_kernel(
    const ushort* __restrict__ nbf, const float* __restrict__ stacks,
    float* __restrict__ pos, float* __restrict__ out) {
  int lane = threadIdx.x & 63;
  int wave = threadIdx.x >> 6;
  if (blockIdx.y < 2) {
    int row = blockIdx.x * 4 + wave;
    int sa = blockIdx.y;
    float a = bf2f(nbf[(size_t)sa * STACK + (size_t)row * ND + lane]);
    float c = bf2f(nbf[(size_t)(sa + 2) * STACK + (size_t)row * ND + lane]);
    float d = wsum(a * c);
    if (lane == 0) pos[sa * NROWS + row] = d;
  } else {
    int b = blockIdx.x * 4 + wave;
    if (b >= NB) return;
    float s = 0.f;
#pragma unroll
    for (int l = 0; l < 3; ++l) {
      size_t o = (size_t)l * NB * ND + (size_t)b * ND + lane;
      s += stacks[0 * (size_t)STACK + o] * stacks[3 * (size_t)STACK + o]
         + stacks[2 * (size_t)STACK + o] * stacks[1 * (size_t)STACK + o];
    }
    s = wsum(s);
    if (lane == 0) out[b] = 1.f / (1.f + __expf(-s));
  }
}

// ---------------- contrastive denominators via MFMA, LDS-staged Y ----------------
__global__ __launch_bounds__(256) void lse_mfma_kernel(
    const ushort* __restrict__ nbf, float* __restrict__ Spart) {
  __shared__ __align__(16) ushort ytile[2][64 * 72];   // 36 KB
  const int tid = threadIdx.x;
  const int wave = tid >> 6, lane = tid & 63;
  const int pair = blockIdx.y;
  const int z = blockIdx.z;
  int xi = (pair & 2) ? ((pair & 1) ? 3 : 1) : ((pair & 1) ? 2 : 0);
  int yi = xi ^ 2;
  const ushort* X = nbf + (size_t)xi * STACK;
  const ushort* Y = nbf + (size_t)yi * STACK;
  const int r0 = blockIdx.x * 64 + wave * 16;
  const int row = lane & 15, quad = lane >> 4;

  short8 a0 = *(const short8*)&X[(size_t)(r0 + row) * 64 + quad * 8];
  short8 a1 = *(const short8*)&X[(size_t)(r0 + row) * 64 + 32 + quad * 8];

  const int srow = tid >> 2, schunk = tid & 3;
  constexpr int NT = (NROWS / NZ) / 64;   // 12 tiles
  const int c0 = z * (NROWS / NZ);
  const ushort* sg = &Y[(size_t)(c0 + srow) * 64 + schunk * 16];
  ushort* sl = &ytile[0][0] + srow * 72 + schunk * 16;

  {
    short8 s0 = *(const short8*)sg;
    short8 s1 = *(const short8*)(sg + 8);
    *(short8*)sl = s0;
    *(short8*)(sl + 8) = s1;
  }
  __syncthreads();

  float rsum[4] = {0.f, 0.f, 0.f, 0.f};
  for (int ct = 0; ct < NT; ++ct) {
    const int cur = ct & 1;
    short8 n0, n1;
    if (ct + 1 < NT) {
      const ushort* src = sg + (size_t)(ct + 1) * 64 * 64;
      n0 = *(const short8*)src;
      n1 = *(const short8*)(src + 8);
    }
#pragma unroll
    for (int nt = 0; nt < 4; ++nt) {
      const ushort* yr = &ytile[cur][(nt * 16 + row) * 72 + quad * 8];
      short8 b0 = *(const short8*)yr;
      short8 b1 = *(const short8*)(yr + 32);
      float4v c = {0.f, 0.f, 0.f, 0.f};
      c = __builtin_amdgcn_mfma_f32_16x16x32_bf16(a0, b0, c, 0, 0, 0);
      c = __builtin_amdgcn_mfma_f32_16x16x32_bf16(a1, b1, c, 0, 0, 0);
#pragma unroll
      for (int i = 0; i < 4; ++i) rsum[i] += __expf(c[i] * 5.f);
    }
    if (ct + 1 < NT) {
      ushort* dst = &ytile[0][0] + ((ct + 1) & 1) * (64 * 72) + srow * 72 + schunk * 16;
      *(short8*)dst = n0;
      *(short8*)(dst + 8) = n1;
      __syncthreads();
    }
  }
#pragma unroll
  for (int i = 0; i < 4; ++i) {
    float v = rsum[i];
    v += __shfl_xor(v, 1, 64);
    v += __shfl_xor(v, 2, 64);
    v += __shfl_xor(v, 4, 64);
    v += __shfl_xor(v, 8, 64);
    if (row == 0)
      Spart[((size_t)z * 4 + pair) * NROWS + r0 + quad * 4 + i] = v;
  }
}

// ---------------- loss: grid-parallel partials + final reduce ----------------
__global__ __launch_bounds__(256) void loss_part_kernel(
    const float* __restrict__ Spart, const float* __restrict__ pos,
    double* __restrict__ lossp) {
  __shared__ double red[256];
  const int t = threadIdx.x, blk = blockIdx.x;
  double acc = 0.0;
#pragma unroll
  for (int r = 0; r < 2; ++r) {
    int i = blk * 512 + r * 256 + t;   // i in [0, 4*NROWS)
    float s = 0.f;
#pragma unroll
    for (int zz = 0; zz < NZ; ++zz) s += Spart[i + zz * 4 * NROWS];
    acc += (double)__logf(s);
  }
  {
    int jj = blk * 256 + t;            // j in [0, 2*NROWS)
    acc -= 10.0 * (double)pos[jj];
  }
  red[t] = acc;
  __syncthreads();
  for (int s = 128; s > 0; s >>= 1) {
    if (t < s) red[t] += red[t + s];
    __syncthreads();
  }
  if (t == 0) lossp[blk] = red[0];
}

__global__ __launch_bounds__(64) void loss_final_kernel(
    const double* __restrict__ lossp, float* __restrict__ out) {
  int lane = threadIdx.x;
  double v = (lane < 48) ? lossp[lane] : 0.0;
#pragma unroll
  for (int o = 32; o > 0; o >>= 1) v += __shfl_xor(v, o, 64);
  if (lane == 0) out[NB] = (float)(1e-6 * v);
}

extern "C" void kernel_launch(void* const* d_in, const int* in_sizes, int n_in,
                              void* d_out, int out_size, void* d_ws, size_t ws_size,
                              hipStream_t stream) {
  const int* items = (const int*)d_in[0];
  const int* ucf_h = (const int*)d_in[1];
  const int* ucf_r = (const int*)d_in[2];
  const int* ucf_t = (const int*)d_in[3];
  const int* ikg_h = (const int*)d_in[4];
  const int* ikg_r = (const int*)d_in[5];
  const int* ikg_t = (const int*)d_in[6];
  const int* ukg_h = (const int*)d_in[7];
  const int* ukg_r = (const int*)d_in[8];
  const int* ukg_t = (const int*)d_in[9];
  const int* icf_h = (const int*)d_in[10];
  const int* icf_r = (const int*)d_in[11];
  const int* icf_t = (const int*)d_in[12];
  const float* E = (const float*)d_in[13];
  const float* R = (const float*)d_in[14];
  const float* att_w1 = (const float*)d_in[15];
  const float* att_w2 = (const float*)d_in[16];
  const float* a2_w1 = (const float*)d_in[17];
  const float* a2_b1 = (const float*)d_in[18];
  const float* a2_w2 = (const float*)d_in[19];
  const float* a2_b2 = (const float*)d_in[20];
  const float* curv = (const float*)d_in[21];
  float* outp = (float*)d_out;

  float* ws = (float*)d_ws;
  float* stacks = ws;                                    // 4*STACK f32
  float* Spart = stacks + 4 * (size_t)STACK;             // NZ*4*NROWS f32
  float* posarr = Spart + (size_t)NZ * 4 * NROWS;        // 2*NROWS f32
  ushort* nbf = (ushort*)(posarr + 2 * (size_t)NROWS);   // 4*STACK bf16
  ushort* w1p_ed = nbf + 4 * (size_t)STACK;              // 8192 ushort
  ushort* w1p_hy = w1p_ed + 8192;                        // 8192 ushort
  double* lossp = (double*)(w1p_hy + 8192);              // 48 doubles

  prep_kernel<<<256, 64, 0, stream>>>(att_w1, a2_w1, w1p_ed, w1p_hy);

  agg_all_kernel<<<dim3(NB, 4), 256, 0, stream>>>(
      E, R, items,
      ucf_h, ucf_r, ucf_t, ikg_h, ikg_r, ikg_t,
      ukg_h, ukg_r, ukg_t, icf_h, icf_r, icf_t,
      w1p_ed, att_w2, w1p_hy, a2_b1, a2_w2, a2_b2, curv,
      stacks, nbf);

  pos_scores_kernel<<<dim3(NROWS / 4, 3), 256, 0, stream>>>(nbf, stacks, posarr, outp);
  lse_mfma_kernel<<<dim3(NROWS / 64, 4, NZ), 256, 0, stream>>>(nbf, Spart);

  loss_part_kernel<<<48, 256, 0, stream>>>(Spart, posarr, lossp);
  loss_final_kernel<<<1, 64, 0, stream>>>(lossp, outp);
}